// Round 4
// baseline (177.204 us; speedup 1.0000x reference)
//
#include <hip/hip_runtime.h>
#include <math.h>

#define B_SZ 32
#define N_NODES 4096
#define C_DIM 64
#define M_EDGES 64
#define DEG 256
#define E_INC 16384
#define NEG_SLOPE 0.2f
#define MARGIN 4.2f

__device__ __forceinline__ float wsum64(float v) {
#pragma unroll
  for (int off = 32; off > 0; off >>= 1) v += __shfl_xor(v, off, 64);
  return v;
}

// node-CSR in one block: LDS count -> wave-shfl scan -> LDS-atomic fill.
// Also zeroes the loss finalization counter (deterministic per call).
__global__ __launch_bounds__(1024) void k_csr(const int* __restrict__ node_ids,
                                              int* __restrict__ row_ptr,
                                              int* __restrict__ csr,
                                              int* __restrict__ counter) {
  __shared__ int cnt[N_NODES];
  __shared__ int rp[N_NODES];
  __shared__ int wtot[16];
  const int t = threadIdx.x;
  if (t == 0) counter[0] = 0;
#pragma unroll
  for (int i = 0; i < 4; ++i) cnt[t + 1024 * i] = 0;
  __syncthreads();
#pragma unroll
  for (int i = 0; i < 16; ++i) atomicAdd(&cnt[node_ids[t + 1024 * i]], 1);
  __syncthreads();
  const int c0 = cnt[4 * t], c1 = cnt[4 * t + 1], c2 = cnt[4 * t + 2],
            c3 = cnt[4 * t + 3];
  const int tsum = c0 + c1 + c2 + c3;
  const int lane = t & 63;
  int v = tsum;
#pragma unroll
  for (int off = 1; off < 64; off <<= 1) {
    const int u = __shfl_up(v, off, 64);
    if (lane >= off) v += u;
  }
  if (lane == 63) wtot[t >> 6] = v;
  __syncthreads();
  if (t == 0) {
    int run = 0;
#pragma unroll
    for (int j = 0; j < 16; ++j) {
      const int xx = wtot[j];
      wtot[j] = run;
      run += xx;
    }
  }
  __syncthreads();
  const int base = wtot[t >> 6] + v - tsum;  // exclusive scan
  rp[4 * t] = base;
  rp[4 * t + 1] = base + c0;
  rp[4 * t + 2] = base + c0 + c1;
  rp[4 * t + 3] = base + c0 + c1 + c2;
#pragma unroll
  for (int i = 0; i < 4; ++i) cnt[t + 1024 * i] = 0;
  __syncthreads();
#pragma unroll
  for (int i = 0; i < 16; ++i) {
    const int e = t + 1024 * i;
    const int n = node_ids[e];
    const int pos = atomicAdd(&cnt[n], 1);
    csr[rp[n] + pos] = e;
  }
#pragma unroll
  for (int i = 0; i < 4; ++i) row_ptr[t + 1024 * i] = rp[t + 1024 * i];
  if (t == 0) row_ptr[N_NODES] = E_INC;
}

// s1_t[n*32+b] = dot(x[b,n,:], W@att0); watt computed per-block in LDS.
__global__ __launch_bounds__(256) void k_s1w(const float* __restrict__ x,
                                             const float* __restrict__ w,
                                             const float* __restrict__ att,
                                             float* __restrict__ s1_t) {
  __shared__ float part[4][64];
  __shared__ float wattl[64];
  const int t = threadIdx.x;
  const int kk = t & 63, q = t >> 6;
  float p = 0.f;
#pragma unroll
  for (int c = 0; c < 16; ++c)
    p = fmaf(w[kk * 64 + q * 16 + c], att[q * 16 + c], p);
  part[q][kk] = p;
  __syncthreads();
  if (t < 64) wattl[t] = part[0][t] + part[1][t] + part[2][t] + part[3][t];
  __syncthreads();
  const int lane = t & 63;
  const int wv = t >> 6;
  const int kq = lane & 15, rsub = lane >> 4;
  const float4 wq = ((const float4*)wattl)[kq];
  const int r0 = blockIdx.x * 256 + wv * 64;
#pragma unroll 4
  for (int it = 0; it < 16; ++it) {
    const int row = r0 + it * 4 + rsub;
    const float4 xv = ((const float4*)x)[row * 16 + kq];
    float v = xv.x * wq.x + xv.y * wq.y + xv.z * wq.z + xv.w * wq.w;
    v += __shfl_xor(v, 1, 64);
    v += __shfl_xor(v, 2, 64);
    v += __shfl_xor(v, 4, 64);
    v += __shfl_xor(v, 8, 64);
    if (kq == 0) {
      const int n = row & (N_NODES - 1);
      const int b = row >> 12;
      s1_t[n * 32 + b] = v;
    }
  }
}

// Per-(m,b) block: 4 waves each sum 64 incidences in x-space, combine in LDS,
// wave 0 does the @W epilogue + s2/nrm2/essum reductions. es_t[m,c,b].
__global__ __launch_bounds__(256) void k_edge2(
    const float* __restrict__ x, const int* __restrict__ node_ids,
    const float* __restrict__ w, const float* __restrict__ att,
    float* __restrict__ es_t, float* __restrict__ s2,
    float* __restrict__ nrm2, float* __restrict__ essum) {
  __shared__ float wl[4096];
  __shared__ float sx[4][64];
  __shared__ float sxc[64];
  const int m = blockIdx.x, b = blockIdx.y;
  const int t = threadIdx.x;
  const int k = t & 63, wv = t >> 6;
  float4* wl4 = (float4*)wl;
  const float4* w4 = (const float4*)w;
#pragma unroll
  for (int i = 0; i < 4; ++i) wl4[t + 256 * i] = w4[t + 256 * i];
  const float* xb = x + (size_t)b * (N_NODES * C_DIM);
  const int ebase = m * DEG + wv * 64;
  float acc = 0.f;
#pragma unroll 16
  for (int i = 0; i < 64; ++i) acc += xb[node_ids[ebase + i] * 64 + k];
  sx[wv][k] = acc;
  __syncthreads();
  if (t < 64) {
    sxc[t] = sx[0][t] + sx[1][t] + sx[2][t] + sx[3][t];
    float es = 0.f;
#pragma unroll 8
    for (int j = 0; j < 64; ++j) es = fmaf(sxc[j], wl[j * 64 + t], es);
    es_t[(m * 64 + t) * 32 + b] = es;
    const float sr = wsum64(es * att[64 + t]);
    const float nr = wsum64(es * es);
    const float er = wsum64(es);
    if (t == 0) {
      s2[m * 32 + b] = sr;
      nrm2[m * 32 + b] = nr;
      essum[m * 32 + b] = er;
    }
  }
}

// lossbuf[p]=|mean_b loss_item|; c-loop split across wave halves.
// Last block (atomic counter) does the deterministic final reduction.
__global__ __launch_bounds__(256) void k_loss2(
    const float* __restrict__ es_t, const float* __restrict__ nrm2,
    const float* __restrict__ essum, float* __restrict__ lossbuf,
    int* __restrict__ counter, float* __restrict__ outs) {
  const int wv = threadIdx.x >> 6;
  const int p = blockIdx.x * 4 + wv;
  const int k = p >> 6, m = p & 63;
  const int lane = threadIdx.x & 63;
  const int b = lane & 31, ch = lane >> 5;
  float inner = 0.f;
#pragma unroll 8
  for (int cc = 0; cc < 32; ++cc) {
    const int c = cc + 32 * ch;
    inner = fmaf(es_t[(k * 64 + c) * 32 + b], es_t[(m * 64 + c) * 32 + b],
                 inner);
  }
  inner += __shfl_xor(inner, 32, 64);
  const float nk2 = nrm2[k * 32 + b];
  const float nm2 = nrm2[m * 32 + b];
  const float d2 = fmaxf(nk2 + nm2 - 2.f * inner, 0.f);
  const float dist = sqrtf(d2);
  const float cosv = inner / sqrtf(nk2 * nm2);
  float li = cosv * dist + (1.f - cosv) * fmaxf(MARGIN - dist, 0.f);
#pragma unroll
  for (int off = 16; off > 0; off >>= 1) li += __shfl_xor(li, off, 64);
  if (lane == 0) lossbuf[p] = fabsf(li * (1.f / 32.f));

  __shared__ int isLast;
  __shared__ float sm[256];
  __threadfence();
  if (threadIdx.x == 0)
    isLast = (atomicAdd(counter, 1) == (int)gridDim.x - 1);
  __syncthreads();
  if (!isLast) return;
  __threadfence();
  const int t = threadIdx.x;
  float s = 0.f;
  for (int i = t; i < M_EDGES * B_SZ; i += 256) s += essum[i];
  sm[t] = s;
  __syncthreads();
  for (int o = 128; o > 0; o >>= 1) {
    if (t < o) sm[t] += sm[t + o];
    __syncthreads();
  }
  const float S = sm[0];
  __syncthreads();
  float l = 0.f;
  for (int i = t; i < M_EDGES * M_EDGES; i += 256) l += lossbuf[i];
  sm[t] = l;
  __syncthreads();
  for (int o = 128; o > 0; o >>= 1) {
    if (t < o) sm[t] += sm[t + o];
    __syncthreads();
  }
  if (t == 0) {
    const float mean = S * (-255.0f) / 33554432.0f;  // sum(x_i-x_j) = -255*S
    outs[0] = fabsf(mean) + sm[0] * (1.0f / 4225.0f);
  }
}

// per-node online softmax -> alpha[e,b]; edge id derived as e>>8
__global__ __launch_bounds__(256) void k_alpha(
    const int* __restrict__ row_ptr, const int* __restrict__ csr,
    const float* __restrict__ s1_t, const float* __restrict__ s2,
    float* __restrict__ alpha) {
  const int n = blockIdx.x * 8 + (threadIdx.x >> 5);
  const int b = threadIdx.x & 31;
  const int rs = row_ptr[n], re = row_ptr[n + 1];
  if (rs == re) return;
  const float s1v = s1_t[n * 32 + b];
  float mx = -1e30f, S = 0.f;
  for (int i = rs; i < re; ++i) {
    const int e = csr[i];
    float sc = s1v + s2[(e >> 8) * 32 + b];
    sc = sc > 0.f ? sc : NEG_SLOPE * sc;
    const float nm = fmaxf(mx, sc);
    S = S * __expf(mx - nm) + __expf(sc - nm);
    mx = nm;
  }
  const float inv = 1.f / S;
  for (int i = rs; i < re; ++i) {
    const int e = csr[i];
    float sc = s1v + s2[(e >> 8) * 32 + b];
    sc = sc > 0.f ? sc : NEG_SLOPE * sc;
    alpha[e * 32 + b] = __expf(sc - mx) * inv;
  }
}

// Per-(m,b) block alpha-weighted x gather + @W epilogue -> out_e_t[m,c,b]/256
__global__ __launch_bounds__(256) void k_oute2(
    const float* __restrict__ x, const int* __restrict__ node_ids,
    const float* __restrict__ w, const float* __restrict__ alpha,
    float* __restrict__ out_e_t) {
  __shared__ float wl[4096];
  __shared__ float sx[4][64];
  __shared__ float sxc[64];
  const int m = blockIdx.x, b = blockIdx.y;
  const int t = threadIdx.x;
  const int k = t & 63, wv = t >> 6;
  float4* wl4 = (float4*)wl;
  const float4* w4 = (const float4*)w;
#pragma unroll
  for (int i = 0; i < 4; ++i) wl4[t + 256 * i] = w4[t + 256 * i];
  const float* xb = x + (size_t)b * (N_NODES * C_DIM);
  const int ebase = m * DEG + wv * 64;
  float acc = 0.f;
#pragma unroll 16
  for (int i = 0; i < 64; ++i) {
    const int e = ebase + i;
    acc = fmaf(alpha[e * 32 + b], xb[node_ids[e] * 64 + k], acc);
  }
  sx[wv][k] = acc;
  __syncthreads();
  if (t < 64) {
    sxc[t] = sx[0][t] + sx[1][t] + sx[2][t] + sx[3][t];
    float oc = 0.f;
#pragma unroll 8
    for (int j = 0; j < 64; ++j) oc = fmaf(sxc[j], wl[j * 64 + t], oc);
    out_e_t[(m * 64 + t) * 32 + b] = oc * (1.0f / 256.0f);
  }
}

// out[b,n,c] = D[n] * sum_{e in node n} alpha[e,b]*out_e_t[m_e,c,b]
__global__ __launch_bounds__(256) void k_out2(
    const int* __restrict__ row_ptr, const int* __restrict__ csr,
    const float* __restrict__ alpha, const float* __restrict__ out_e_t,
    float* __restrict__ out) {
  const int n = blockIdx.x;
  const int c = threadIdx.x & 63, bq = threadIdx.x >> 6;
  const int rs = row_ptr[n], re = row_ptr[n + 1];
  float4 a0 = {0.f, 0.f, 0.f, 0.f}, a1 = {0.f, 0.f, 0.f, 0.f};
  for (int i = rs; i < re; ++i) {
    const int e = csr[i];
    const int m = e >> 8;
    const float4 al0 = *(const float4*)&alpha[e * 32 + bq * 8];
    const float4 al1 = *(const float4*)&alpha[e * 32 + bq * 8 + 4];
    const float4 v0 = *(const float4*)&out_e_t[(m * 64 + c) * 32 + bq * 8];
    const float4 v1 = *(const float4*)&out_e_t[(m * 64 + c) * 32 + bq * 8 + 4];
    a0.x = fmaf(al0.x, v0.x, a0.x);
    a0.y = fmaf(al0.y, v0.y, a0.y);
    a0.z = fmaf(al0.z, v0.z, a0.z);
    a0.w = fmaf(al0.w, v0.w, a0.w);
    a1.x = fmaf(al1.x, v1.x, a1.x);
    a1.y = fmaf(al1.y, v1.y, a1.y);
    a1.z = fmaf(al1.z, v1.z, a1.z);
    a1.w = fmaf(al1.w, v1.w, a1.w);
  }
  const float Dn = (float)(re - rs);
  const size_t nb = (size_t)n * 64 + c;
  const size_t st = (size_t)N_NODES * 64;
  out[(bq * 8 + 0) * st + nb] = Dn * a0.x;
  out[(bq * 8 + 1) * st + nb] = Dn * a0.y;
  out[(bq * 8 + 2) * st + nb] = Dn * a0.z;
  out[(bq * 8 + 3) * st + nb] = Dn * a0.w;
  out[(bq * 8 + 4) * st + nb] = Dn * a1.x;
  out[(bq * 8 + 5) * st + nb] = Dn * a1.y;
  out[(bq * 8 + 6) * st + nb] = Dn * a1.z;
  out[(bq * 8 + 7) * st + nb] = Dn * a1.w;
}

extern "C" void kernel_launch(void* const* d_in, const int* in_sizes, int n_in,
                              void* d_out, int out_size, void* d_ws,
                              size_t ws_size, hipStream_t stream) {
  (void)in_sizes; (void)n_in; (void)out_size; (void)ws_size;
  const float* x = (const float*)d_in[0];
  const float* weight = (const float*)d_in[1];
  const float* att = (const float*)d_in[2];
  const int* node_ids = (const int*)d_in[3];
  float* out = (float*)d_out;

  char* wsb = (char*)d_ws;
  float* es_t = (float*)(wsb);                    // 512KB [m,c,b]
  float* out_e_t = (float*)(wsb + (512 << 10));   // 512KB [m,c,b]
  float* s1_t = (float*)(wsb + (1024 << 10));     // 512KB [n,b]
  float* alpha = (float*)(wsb + (1536 << 10));    // 2MB   [e,b]
  float* s2 = (float*)(wsb + (3584 << 10));       // 8KB
  float* nrm2 = (float*)(wsb + (3592 << 10));     // 8KB
  float* essum = (float*)(wsb + (3600 << 10));    // 8KB
  float* lossbuf = (float*)(wsb + (3608 << 10));  // 16KB
  int* row_ptr = (int*)(wsb + (3624 << 10));      // 20KB (4097 ints)
  int* csr = (int*)(wsb + (3644 << 10));          // 64KB
  int* counter = (int*)(wsb + (3710 << 10));      // 4B

  k_csr<<<1, 1024, 0, stream>>>(node_ids, row_ptr, csr, counter);
  k_s1w<<<512, 256, 0, stream>>>(x, weight, att, s1_t);
  k_edge2<<<dim3(M_EDGES, B_SZ), 256, 0, stream>>>(x, node_ids, weight, att,
                                                   es_t, s2, nrm2, essum);
  k_loss2<<<(M_EDGES * M_EDGES) / 4, 256, 0, stream>>>(
      es_t, nrm2, essum, lossbuf, counter,
      out + (size_t)B_SZ * N_NODES * C_DIM);
  k_alpha<<<N_NODES / 8, 256, 0, stream>>>(row_ptr, csr, s1_t, s2, alpha);
  k_oute2<<<dim3(M_EDGES, B_SZ), 256, 0, stream>>>(x, node_ids, weight, alpha,
                                                   out_e_t);
  k_out2<<<N_NODES, 256, 0, stream>>>(row_ptr, csr, alpha, out_e_t, out);
}

// Round 5
// 109.454 us; speedup vs baseline: 1.6190x; 1.6190x over previous
//
#include <hip/hip_runtime.h>
#include <math.h>

#define B_SZ 32
#define N_NODES 4096
#define C_DIM 64
#define M_EDGES 64
#define DEG 256
#define E_INC 16384
#define NEG_SLOPE 0.2f
#define MARGIN 4.2f

__device__ __forceinline__ float wsum64(float v) {
#pragma unroll
  for (int off = 32; off > 0; off >>= 1) v += __shfl_xor(v, off, 64);
  return v;
}

union SmemP1 {
  struct {
    float wl[4096];
    float sx[4][64];
    float sxc[64];
  } e;
  struct {
    int cnt[N_NODES];
    int wtot[4];
  } c;
  struct {
    float part[4][64];
    float wattl[64];
  } s;
};

// Phase 1 (fused): bid<2048 edge-sums (XCD-swizzled), bid==2048 CSR build,
// bid>2048 s1 streaming pass.
__global__ __launch_bounds__(256) void k_p1(
    const float* __restrict__ x, const float* __restrict__ w,
    const float* __restrict__ att, const int* __restrict__ node_ids,
    int* __restrict__ row_ptr, int* __restrict__ csr,
    float* __restrict__ s1_t, float* __restrict__ es_t,
    float* __restrict__ s2, float* __restrict__ nrm2,
    float* __restrict__ essum) {
  __shared__ SmemP1 sm;
  const int bid = blockIdx.x;
  const int t = threadIdx.x;
  if (bid < 2048) {
    // ---- edge-sum role: block owns (m,b); XCD gets 4 b-panels (L2-resident)
    const int b = 4 * (bid & 7) + ((bid >> 3) & 3);
    const int m = bid >> 5;
    const int k = t & 63, wv = t >> 6;
    float4* wl4 = (float4*)sm.e.wl;
    const float4* w4 = (const float4*)w;
#pragma unroll
    for (int i = 0; i < 4; ++i) wl4[t + 256 * i] = w4[t + 256 * i];
    const float* xb = x + (size_t)b * (N_NODES * C_DIM);
    const int ebase = m * DEG + wv * 64;
    float acc = 0.f;
#pragma unroll 16
    for (int i = 0; i < 64; ++i) acc += xb[node_ids[ebase + i] * 64 + k];
    sm.e.sx[wv][k] = acc;
    __syncthreads();
    if (t < 64) {
      const float sv =
          sm.e.sx[0][t] + sm.e.sx[1][t] + sm.e.sx[2][t] + sm.e.sx[3][t];
      sm.e.sxc[t] = sv;
      float es = 0.f;
#pragma unroll 8
      for (int j = 0; j < 64; ++j) es = fmaf(sm.e.sxc[j], sm.e.wl[j * 64 + t], es);
      es_t[(m * 64 + t) * 32 + b] = es;
      const float sr = wsum64(es * att[64 + t]);
      const float nr = wsum64(es * es);
      const float er = wsum64(es);
      if (t == 0) {
        s2[m * 32 + b] = sr;
        nrm2[m * 32 + b] = nr;
        essum[m * 32 + b] = er;
      }
    }
  } else if (bid == 2048) {
    // ---- CSR role: count -> scan -> fill (one block, 256 threads)
#pragma unroll
    for (int i = 0; i < 16; ++i) sm.c.cnt[t + 256 * i] = 0;
    __syncthreads();
#pragma unroll
    for (int i = 0; i < 64; ++i) atomicAdd(&sm.c.cnt[node_ids[t + 256 * i]], 1);
    __syncthreads();
    int loc[16];
    int run = 0;
#pragma unroll
    for (int i = 0; i < 16; ++i) {
      run += sm.c.cnt[t * 16 + i];
      loc[i] = run;
    }
    const int lane = t & 63, wv = t >> 6;
    int v = run;
#pragma unroll
    for (int off = 1; off < 64; off <<= 1) {
      const int u = __shfl_up(v, off, 64);
      if (lane >= off) v += u;
    }
    if (lane == 63) sm.c.wtot[wv] = v;
    __syncthreads();
    if (t == 0) {
      int r2 = 0;
#pragma unroll
      for (int j = 0; j < 4; ++j) {
        const int xx = sm.c.wtot[j];
        sm.c.wtot[j] = r2;
        r2 += xx;
      }
    }
    __syncthreads();
    const int base = sm.c.wtot[wv] + v - run;  // exclusive start of chunk
#pragma unroll
    for (int i = 0; i < 16; ++i) row_ptr[t * 16 + i + 1] = base + loc[i];
    if (t == 0) row_ptr[0] = 0;
    // reset counts, then fill (row_ptr reads via global, block-visible after sync)
#pragma unroll
    for (int i = 0; i < 16; ++i) sm.c.cnt[t + 256 * i] = 0;
    __syncthreads();
#pragma unroll
    for (int i = 0; i < 64; ++i) {
      const int e = t + 256 * i;
      const int n = node_ids[e];
      const int pos = atomicAdd(&sm.c.cnt[n], 1);
      csr[row_ptr[n] + pos] = e;
    }
  } else {
    // ---- s1 role: s1_t[n*32+b] = dot(x[b,n,:], W@att0)
    const int sb = bid - 2049;
    const int kk = t & 63, q = t >> 6;
    float p = 0.f;
#pragma unroll
    for (int c = 0; c < 16; ++c)
      p = fmaf(w[kk * 64 + q * 16 + c], att[q * 16 + c], p);
    sm.s.part[q][kk] = p;
    __syncthreads();
    if (t < 64)
      sm.s.wattl[t] =
          sm.s.part[0][t] + sm.s.part[1][t] + sm.s.part[2][t] + sm.s.part[3][t];
    __syncthreads();
    const int lane = t & 63, wv = t >> 6;
    const int kq = lane & 15, rsub = lane >> 4;
    const float4 wq = ((const float4*)sm.s.wattl)[kq];
    const int r0 = sb * 256 + wv * 64;
#pragma unroll 4
    for (int it = 0; it < 16; ++it) {
      const int row = r0 + it * 4 + rsub;
      const float4 xv = ((const float4*)x)[row * 16 + kq];
      float vv = xv.x * wq.x + xv.y * wq.y + xv.z * wq.z + xv.w * wq.w;
      vv += __shfl_xor(vv, 1, 64);
      vv += __shfl_xor(vv, 2, 64);
      vv += __shfl_xor(vv, 4, 64);
      vv += __shfl_xor(vv, 8, 64);
      if (kq == 0) {
        const int n = row & (N_NODES - 1);
        const int b = row >> 12;
        s1_t[n * 32 + b] = vv;
      }
    }
  }
}

// Phase 2 (fused): bid<1024 pairwise loss, bid>=1024 per-node softmax alpha.
__global__ __launch_bounds__(256) void k_p2(
    const float* __restrict__ es_t, const float* __restrict__ nrm2,
    const int* __restrict__ row_ptr, const int* __restrict__ csr,
    const float* __restrict__ s1_t, const float* __restrict__ s2,
    float* __restrict__ lossbuf, float* __restrict__ alpha) {
  const int bid = blockIdx.x;
  if (bid < 1024) {
    const int wv = threadIdx.x >> 6;
    const int p = bid * 4 + wv;
    const int k = p >> 6, m = p & 63;
    const int lane = threadIdx.x & 63;
    const int b = lane & 31, ch = lane >> 5;
    float inner = 0.f;
#pragma unroll 8
    for (int cc = 0; cc < 32; ++cc) {
      const int c = cc + 32 * ch;
      inner = fmaf(es_t[(k * 64 + c) * 32 + b], es_t[(m * 64 + c) * 32 + b],
                   inner);
    }
    inner += __shfl_xor(inner, 32, 64);
    const float nk2 = nrm2[k * 32 + b];
    const float nm2 = nrm2[m * 32 + b];
    const float d2 = fmaxf(nk2 + nm2 - 2.f * inner, 0.f);
    const float dist = sqrtf(d2);
    const float cosv = inner / sqrtf(nk2 * nm2);
    float li = cosv * dist + (1.f - cosv) * fmaxf(MARGIN - dist, 0.f);
#pragma unroll
    for (int off = 16; off > 0; off >>= 1) li += __shfl_xor(li, off, 64);
    if (lane == 0) lossbuf[p] = fabsf(li * (1.f / 32.f));
  } else {
    const int n = (bid - 1024) * 8 + (threadIdx.x >> 5);
    const int b = threadIdx.x & 31;
    const int rs = row_ptr[n], re = row_ptr[n + 1];
    if (rs == re) return;
    const float s1v = s1_t[n * 32 + b];
    float mx = -1e30f, S = 0.f;
    for (int i = rs; i < re; ++i) {
      const int e = csr[i];
      float sc = s1v + s2[(e >> 8) * 32 + b];
      sc = sc > 0.f ? sc : NEG_SLOPE * sc;
      const float nm = fmaxf(mx, sc);
      S = S * __expf(mx - nm) + __expf(sc - nm);
      mx = nm;
    }
    const float inv = 1.f / S;
    for (int i = rs; i < re; ++i) {
      const int e = csr[i];
      float sc = s1v + s2[(e >> 8) * 32 + b];
      sc = sc > 0.f ? sc : NEG_SLOPE * sc;
      alpha[e * 32 + b] = __expf(sc - mx) * inv;
    }
  }
}

// Phase 3 (fused): bid<2048 out_e gather (XCD-swizzled), bid==2048 final scalar.
__global__ __launch_bounds__(256) void k_p3(
    const float* __restrict__ x, const int* __restrict__ node_ids,
    const float* __restrict__ w, const float* __restrict__ alpha,
    const float* __restrict__ essum, const float* __restrict__ lossbuf,
    float* __restrict__ out_e_t, float* __restrict__ outs) {
  __shared__ SmemP1 sm;
  const int bid = blockIdx.x;
  const int t = threadIdx.x;
  if (bid < 2048) {
    const int b = 4 * (bid & 7) + ((bid >> 3) & 3);
    const int m = bid >> 5;
    const int k = t & 63, wv = t >> 6;
    float4* wl4 = (float4*)sm.e.wl;
    const float4* w4 = (const float4*)w;
#pragma unroll
    for (int i = 0; i < 4; ++i) wl4[t + 256 * i] = w4[t + 256 * i];
    const float* xb = x + (size_t)b * (N_NODES * C_DIM);
    const int ebase = m * DEG + wv * 64;
    float acc = 0.f;
#pragma unroll 16
    for (int i = 0; i < 64; ++i) {
      const int e = ebase + i;
      acc = fmaf(alpha[e * 32 + b], xb[node_ids[e] * 64 + k], acc);
    }
    sm.e.sx[wv][k] = acc;
    __syncthreads();
    if (t < 64) {
      sm.e.sxc[t] =
          sm.e.sx[0][t] + sm.e.sx[1][t] + sm.e.sx[2][t] + sm.e.sx[3][t];
      float oc = 0.f;
#pragma unroll 8
      for (int j = 0; j < 64; ++j)
        oc = fmaf(sm.e.sxc[j], sm.e.wl[j * 64 + t], oc);
      out_e_t[(m * 64 + t) * 32 + b] = oc * (1.0f / 256.0f);
    }
  } else {
    // final scalar: deterministic block reduction of essum + lossbuf
    __shared__ float smf[256];
    float s = 0.f;
    for (int i = t; i < M_EDGES * B_SZ; i += 256) s += essum[i];
    smf[t] = s;
    __syncthreads();
    for (int o = 128; o > 0; o >>= 1) {
      if (t < o) smf[t] += smf[t + o];
      __syncthreads();
    }
    const float S = smf[0];
    __syncthreads();
    float l = 0.f;
    for (int i = t; i < M_EDGES * M_EDGES; i += 256) l += lossbuf[i];
    smf[t] = l;
    __syncthreads();
    for (int o = 128; o > 0; o >>= 1) {
      if (t < o) smf[t] += smf[t + o];
      __syncthreads();
    }
    if (t == 0) {
      const float mean = S * (-255.0f) / 33554432.0f;  // sum(x_i-x_j) = -255*S
      outs[0] = fabsf(mean) + smf[0] * (1.0f / 4225.0f);
    }
  }
}

// Phase 4: out[b,n,c] = D[n] * sum_{e in node n} alpha[e,b]*out_e_t[m_e,c,b]
__global__ __launch_bounds__(256) void k_p4(
    const int* __restrict__ row_ptr, const int* __restrict__ csr,
    const float* __restrict__ alpha, const float* __restrict__ out_e_t,
    float* __restrict__ out) {
  const int n = blockIdx.x;
  const int c = threadIdx.x & 63, bq = threadIdx.x >> 6;
  const int rs = row_ptr[n], re = row_ptr[n + 1];
  float4 a0 = {0.f, 0.f, 0.f, 0.f}, a1 = {0.f, 0.f, 0.f, 0.f};
  for (int i = rs; i < re; ++i) {
    const int e = csr[i];
    const int m = e >> 8;
    const float4 al0 = *(const float4*)&alpha[e * 32 + bq * 8];
    const float4 al1 = *(const float4*)&alpha[e * 32 + bq * 8 + 4];
    const float4 v0 = *(const float4*)&out_e_t[(m * 64 + c) * 32 + bq * 8];
    const float4 v1 = *(const float4*)&out_e_t[(m * 64 + c) * 32 + bq * 8 + 4];
    a0.x = fmaf(al0.x, v0.x, a0.x);
    a0.y = fmaf(al0.y, v0.y, a0.y);
    a0.z = fmaf(al0.z, v0.z, a0.z);
    a0.w = fmaf(al0.w, v0.w, a0.w);
    a1.x = fmaf(al1.x, v1.x, a1.x);
    a1.y = fmaf(al1.y, v1.y, a1.y);
    a1.z = fmaf(al1.z, v1.z, a1.z);
    a1.w = fmaf(al1.w, v1.w, a1.w);
  }
  const float Dn = (float)(re - rs);
  const size_t nb = (size_t)n * 64 + c;
  const size_t st = (size_t)N_NODES * 64;
  out[(bq * 8 + 0) * st + nb] = Dn * a0.x;
  out[(bq * 8 + 1) * st + nb] = Dn * a0.y;
  out[(bq * 8 + 2) * st + nb] = Dn * a0.z;
  out[(bq * 8 + 3) * st + nb] = Dn * a0.w;
  out[(bq * 8 + 4) * st + nb] = Dn * a1.x;
  out[(bq * 8 + 5) * st + nb] = Dn * a1.y;
  out[(bq * 8 + 6) * st + nb] = Dn * a1.z;
  out[(bq * 8 + 7) * st + nb] = Dn * a1.w;
}

extern "C" void kernel_launch(void* const* d_in, const int* in_sizes, int n_in,
                              void* d_out, int out_size, void* d_ws,
                              size_t ws_size, hipStream_t stream) {
  (void)in_sizes; (void)n_in; (void)out_size; (void)ws_size;
  const float* x = (const float*)d_in[0];
  const float* weight = (const float*)d_in[1];
  const float* att = (const float*)d_in[2];
  const int* node_ids = (const int*)d_in[3];
  float* out = (float*)d_out;

  char* wsb = (char*)d_ws;
  float* es_t = (float*)(wsb);                    // 512KB [m,c,b]
  float* out_e_t = (float*)(wsb + (512 << 10));   // 512KB [m,c,b]
  float* s1_t = (float*)(wsb + (1024 << 10));     // 512KB [n,b]
  float* alpha = (float*)(wsb + (1536 << 10));    // 2MB   [e,b]
  float* s2 = (float*)(wsb + (3584 << 10));       // 8KB
  float* nrm2 = (float*)(wsb + (3592 << 10));     // 8KB
  float* essum = (float*)(wsb + (3600 << 10));    // 8KB
  float* lossbuf = (float*)(wsb + (3608 << 10));  // 16KB
  int* row_ptr = (int*)(wsb + (3624 << 10));      // 20KB (4097 ints)
  int* csr = (int*)(wsb + (3644 << 10));          // 64KB

  k_p1<<<2561, 256, 0, stream>>>(x, weight, att, node_ids, row_ptr, csr, s1_t,
                                 es_t, s2, nrm2, essum);
  k_p2<<<1536, 256, 0, stream>>>(es_t, nrm2, row_ptr, csr, s1_t, s2, lossbuf,
                                 alpha);
  k_p3<<<2049, 256, 0, stream>>>(x, node_ids, weight, alpha, essum, lossbuf,
                                 out_e_t, out + (size_t)B_SZ * N_NODES * C_DIM);
  k_p4<<<4096, 256, 0, stream>>>(row_ptr, csr, alpha, out_e_t, out);
}

// Round 6
// 91.438 us; speedup vs baseline: 1.9380x; 1.1970x over previous
//
#include <hip/hip_runtime.h>
#include <math.h>

#define B_SZ 32
#define N_NODES 4096
#define C_DIM 64
#define M_EDGES 64
#define DEG 256
#define E_INC 16384
#define NEG_SLOPE 0.2f
#define MARGIN 4.2f

__device__ __forceinline__ float wsum64(float v) {
#pragma unroll
  for (int off = 32; off > 0; off >>= 1) v += __shfl_xor(v, off, 64);
  return v;
}

__device__ __forceinline__ float4 redq16_32(float4 a) {
#pragma unroll
  for (int off = 16; off < 64; off <<= 1) {
    a.x += __shfl_xor(a.x, off, 64);
    a.y += __shfl_xor(a.y, off, 64);
    a.z += __shfl_xor(a.z, off, 64);
    a.w += __shfl_xor(a.w, off, 64);
  }
  return a;
}

union SmemBig {
  struct {
    float wl[4096];
    float sx[4][64];
    float sxc[64];
  } e;
  struct {
    int cnt[N_NODES];
  } c;
  struct {
    float part[4][64];
    float wattl[64];
  } s;
};

// P1: bid<2048 edge-sum gather (float4, XCD-swizzled b); bid<2112 per-edge
// incidence-count rows (coalesced, deterministic); else s1 streaming pass.
__global__ __launch_bounds__(256) void k_p1(
    const float* __restrict__ x, const float* __restrict__ w,
    const float* __restrict__ att, const int* __restrict__ node_ids,
    float* __restrict__ s1_t, float* __restrict__ es_t,
    float* __restrict__ s2, float* __restrict__ nrm2,
    float* __restrict__ essum, int* __restrict__ cntv) {
  __shared__ SmemBig sm;
  const int bid = blockIdx.x;
  const int t = threadIdx.x;
  if (bid < 2048) {
    const int b = 4 * (bid & 7) + ((bid >> 3) & 3);
    const int m = bid >> 5;
    const int lane = t & 63, wv = t >> 6;
    const int qc = lane & 15, rsub = lane >> 4;
    float4* wl4 = (float4*)sm.e.wl;
    const float4* w4 = (const float4*)w;
#pragma unroll
    for (int i = 0; i < 4; ++i) wl4[t + 256 * i] = w4[t + 256 * i];
    const float4* xb4 = (const float4*)(x + (size_t)b * (N_NODES * C_DIM));
    const int rbase = m * DEG + wv * 64 + rsub;
    float4 acc = {0.f, 0.f, 0.f, 0.f};
#pragma unroll
    for (int i = 0; i < 16; ++i) {
      const int node = node_ids[rbase + i * 4];
      const float4 xv = xb4[node * 16 + qc];
      acc.x += xv.x;
      acc.y += xv.y;
      acc.z += xv.z;
      acc.w += xv.w;
    }
    acc = redq16_32(acc);
    if (rsub == 0) ((float4*)sm.e.sx[wv])[qc] = acc;
    __syncthreads();
    if (t < 64) {
      sm.e.sxc[t] =
          sm.e.sx[0][t] + sm.e.sx[1][t] + sm.e.sx[2][t] + sm.e.sx[3][t];
      float es = 0.f;
#pragma unroll 8
      for (int j = 0; j < 64; ++j)
        es = fmaf(sm.e.sxc[j], sm.e.wl[j * 64 + t], es);
      es_t[(m * 64 + t) * 32 + b] = es;
      const float sr = wsum64(es * att[64 + t]);
      const float nr = wsum64(es * es);
      const float er = wsum64(es);
      if (t == 0) {
        s2[m * 32 + b] = sr;
        nrm2[m * 32 + b] = nr;
        essum[m * 32 + b] = er;
      }
    }
  } else if (bid < 2112) {
    // per-edge counts: cntv[m][n] (coalesced row write, no scatter)
    const int m = bid - 2048;
#pragma unroll
    for (int i = 0; i < 16; ++i) sm.c.cnt[t + 256 * i] = 0;
    __syncthreads();
    atomicAdd(&sm.c.cnt[node_ids[m * DEG + t]], 1);
    __syncthreads();
#pragma unroll
    for (int i = 0; i < 16; ++i)
      cntv[m * N_NODES + t + 256 * i] = sm.c.cnt[t + 256 * i];
  } else {
    // s1 role: s1_t[n*32+b] = dot(x[b,n,:], W@att0)
    const int sb = bid - 2112;
    const int kk = t & 63, q = t >> 6;
    float p = 0.f;
#pragma unroll
    for (int c = 0; c < 16; ++c)
      p = fmaf(w[kk * 64 + q * 16 + c], att[q * 16 + c], p);
    sm.s.part[q][kk] = p;
    __syncthreads();
    if (t < 64)
      sm.s.wattl[t] =
          sm.s.part[0][t] + sm.s.part[1][t] + sm.s.part[2][t] + sm.s.part[3][t];
    __syncthreads();
    const int lane = t & 63, wv = t >> 6;
    const int kq = lane & 15, rsub = lane >> 4;
    const float4 wq = ((const float4*)sm.s.wattl)[kq];
    const int r0 = sb * 256 + wv * 64;
#pragma unroll 4
    for (int it = 0; it < 16; ++it) {
      const int row = r0 + it * 4 + rsub;
      const float4 xv = ((const float4*)x)[row * 16 + kq];
      float vv = xv.x * wq.x + xv.y * wq.y + xv.z * wq.z + xv.w * wq.w;
      vv += __shfl_xor(vv, 1, 64);
      vv += __shfl_xor(vv, 2, 64);
      vv += __shfl_xor(vv, 4, 64);
      vv += __shfl_xor(vv, 8, 64);
      if (kq == 0) {
        const int n = row & (N_NODES - 1);
        const int b = row >> 12;
        s1_t[n * 32 + b] = vv;
      }
    }
  }
}

// P2: bid<1024 pairwise loss; else per-(n,b) softmax state {mx, 1/S} via cntv.
__global__ __launch_bounds__(256) void k_p2(
    const float* __restrict__ es_t, const float* __restrict__ nrm2,
    const int* __restrict__ cntv, const float* __restrict__ s1_t,
    const float* __restrict__ s2, float* __restrict__ lossbuf,
    float2* __restrict__ pnb) {
  const int bid = blockIdx.x;
  if (bid < 1024) {
    const int wv = threadIdx.x >> 6;
    const int p = bid * 4 + wv;
    const int k = p >> 6, m = p & 63;
    const int lane = threadIdx.x & 63;
    const int b = lane & 31, ch = lane >> 5;
    float inner = 0.f;
#pragma unroll 8
    for (int cc = 0; cc < 32; ++cc) {
      const int c = cc + 32 * ch;
      inner = fmaf(es_t[(k * 64 + c) * 32 + b], es_t[(m * 64 + c) * 32 + b],
                   inner);
    }
    inner += __shfl_xor(inner, 32, 64);
    const float nk2 = nrm2[k * 32 + b];
    const float nm2 = nrm2[m * 32 + b];
    const float d2 = fmaxf(nk2 + nm2 - 2.f * inner, 0.f);
    const float dist = sqrtf(d2);
    const float cosv = inner / sqrtf(nk2 * nm2);
    float li = cosv * dist + (1.f - cosv) * fmaxf(MARGIN - dist, 0.f);
#pragma unroll
    for (int off = 16; off > 0; off >>= 1) li += __shfl_xor(li, off, 64);
    if (lane == 0) lossbuf[p] = fabsf(li * (1.f / 32.f));
  } else {
    const int idx = (bid - 1024) * 256 + threadIdx.x;
    const int n = idx >> 5, b = idx & 31;
    const float s1v = s1_t[n * 32 + b];
    float mx = -1e30f, S = 0.f;
#pragma unroll 4
    for (int m = 0; m < 64; ++m) {
      const int cm = cntv[m * N_NODES + n];
      if (cm > 0) {
        float sc = s1v + s2[m * 32 + b];
        sc = sc > 0.f ? sc : NEG_SLOPE * sc;
        const float nm = fmaxf(mx, sc);
        S = S * __expf(mx - nm) + (float)cm * __expf(sc - nm);
        mx = nm;
      }
    }
    float2 pv;
    pv.x = mx;
    pv.y = (S > 0.f) ? 1.f / S : 0.f;
    pnb[n * 32 + b] = pv;
  }
}

// P3: bid<2048 out_e gather with on-the-fly alpha; bid==2048 final scalar.
__global__ __launch_bounds__(256) void k_p3(
    const float* __restrict__ x, const int* __restrict__ node_ids,
    const float* __restrict__ w, const float* __restrict__ s1_t,
    const float* __restrict__ s2, const float2* __restrict__ pnb,
    const float* __restrict__ essum, const float* __restrict__ lossbuf,
    float* __restrict__ out_e_t, float* __restrict__ outs) {
  __shared__ SmemBig sm;
  const int bid = blockIdx.x;
  const int t = threadIdx.x;
  if (bid < 2048) {
    const int b = 4 * (bid & 7) + ((bid >> 3) & 3);
    const int m = bid >> 5;
    const int lane = t & 63, wv = t >> 6;
    const int qc = lane & 15, rsub = lane >> 4;
    float4* wl4 = (float4*)sm.e.wl;
    const float4* w4 = (const float4*)w;
#pragma unroll
    for (int i = 0; i < 4; ++i) wl4[t + 256 * i] = w4[t + 256 * i];
    const float4* xb4 = (const float4*)(x + (size_t)b * (N_NODES * C_DIM));
    const float s2mb = s2[m * 32 + b];
    const int rbase = m * DEG + wv * 64 + rsub;
    float4 acc = {0.f, 0.f, 0.f, 0.f};
#pragma unroll
    for (int i = 0; i < 16; ++i) {
      const int node = node_ids[rbase + i * 4];
      const float s1v = s1_t[node * 32 + b];
      const float2 pv = pnb[node * 32 + b];
      float sc = s1v + s2mb;
      sc = sc > 0.f ? sc : NEG_SLOPE * sc;
      const float a = __expf(sc - pv.x) * pv.y;
      const float4 xv = xb4[node * 16 + qc];
      acc.x = fmaf(a, xv.x, acc.x);
      acc.y = fmaf(a, xv.y, acc.y);
      acc.z = fmaf(a, xv.z, acc.z);
      acc.w = fmaf(a, xv.w, acc.w);
    }
    acc = redq16_32(acc);
    if (rsub == 0) ((float4*)sm.e.sx[wv])[qc] = acc;
    __syncthreads();
    if (t < 64) {
      sm.e.sxc[t] =
          sm.e.sx[0][t] + sm.e.sx[1][t] + sm.e.sx[2][t] + sm.e.sx[3][t];
      float oc = 0.f;
#pragma unroll 8
      for (int j = 0; j < 64; ++j)
        oc = fmaf(sm.e.sxc[j], sm.e.wl[j * 64 + t], oc);
      out_e_t[(m * 64 + t) * 32 + b] = oc * (1.0f / 256.0f);
    }
  } else {
    __shared__ float smf[256];
    float s = 0.f;
    for (int i = t; i < M_EDGES * B_SZ; i += 256) s += essum[i];
    smf[t] = s;
    __syncthreads();
    for (int o = 128; o > 0; o >>= 1) {
      if (t < o) smf[t] += smf[t + o];
      __syncthreads();
    }
    const float S = smf[0];
    __syncthreads();
    float l = 0.f;
    for (int i = t; i < M_EDGES * M_EDGES; i += 256) l += lossbuf[i];
    smf[t] = l;
    __syncthreads();
    for (int o = 128; o > 0; o >>= 1) {
      if (t < o) smf[t] += smf[t + o];
      __syncthreads();
    }
    if (t == 0) {
      const float mean = S * (-255.0f) / 33554432.0f;  // sum(x_i-x_j)=-255*S
      outs[0] = fabsf(mean) + smf[0] * (1.0f / 4225.0f);
    }
  }
}

// P4: per node, deterministic nonzero-edge list via ballot; alpha in LDS;
// out[b,n,c] = D[n] * sum_m cnt*alpha(n,m,b)*out_e_t[m,c,b]
__global__ __launch_bounds__(256) void k_p4(
    const int* __restrict__ cntv, const float* __restrict__ s1_t,
    const float* __restrict__ s2, const float2* __restrict__ pnb,
    const float* __restrict__ out_e_t, float* __restrict__ out) {
  __shared__ int listm[64];
  __shared__ int cl[64];
  __shared__ float al[64][32];
  __shared__ float DnS;
  __shared__ int llenS;
  const int n = blockIdx.x;
  const int t = threadIdx.x;
  if (t < 64) {
    const int cv = cntv[t * N_NODES + n];
    cl[t] = cv;
    const unsigned long long mask = __ballot(cv > 0);
    const int pos = __popcll(mask & ((1ull << t) - 1ull));
    if (cv > 0) listm[pos] = t;
    const float d = wsum64((float)cv);
    if (t == 0) {
      llenS = __popcll(mask);
      DnS = d;
    }
  }
  __syncthreads();
  const int llen = llenS;
  const int c = t & 63, bq = t >> 6;
  const size_t nb = (size_t)n * 64 + c;
  const size_t st = (size_t)N_NODES * 64;
  if (llen == 0) {
#pragma unroll
    for (int j = 0; j < 8; ++j) out[(bq * 8 + j) * st + nb] = 0.f;
    return;
  }
  {
    const int b = t & 31, lq = t >> 5;
    const float s1v = s1_t[n * 32 + b];
    const float2 pv = pnb[n * 32 + b];
    for (int base = 0; base < llen; base += 8) {
      const int li = base + lq;
      if (li < llen) {
        const int m = listm[li];
        float sc = s1v + s2[m * 32 + b];
        sc = sc > 0.f ? sc : NEG_SLOPE * sc;
        al[li][b] = (float)cl[m] * __expf(sc - pv.x) * pv.y;
      }
    }
  }
  __syncthreads();
  float4 a0 = {0.f, 0.f, 0.f, 0.f}, a1 = {0.f, 0.f, 0.f, 0.f};
  for (int li = 0; li < llen; ++li) {
    const int m = listm[li];
    const float4 v0 = *(const float4*)&out_e_t[(m * 64 + c) * 32 + bq * 8];
    const float4 v1 = *(const float4*)&out_e_t[(m * 64 + c) * 32 + bq * 8 + 4];
    const float* alr = al[li];
    a0.x = fmaf(alr[bq * 8 + 0], v0.x, a0.x);
    a0.y = fmaf(alr[bq * 8 + 1], v0.y, a0.y);
    a0.z = fmaf(alr[bq * 8 + 2], v0.z, a0.z);
    a0.w = fmaf(alr[bq * 8 + 3], v0.w, a0.w);
    a1.x = fmaf(alr[bq * 8 + 4], v1.x, a1.x);
    a1.y = fmaf(alr[bq * 8 + 5], v1.y, a1.y);
    a1.z = fmaf(alr[bq * 8 + 6], v1.z, a1.z);
    a1.w = fmaf(alr[bq * 8 + 7], v1.w, a1.w);
  }
  const float Dn = DnS;
  out[(bq * 8 + 0) * st + nb] = Dn * a0.x;
  out[(bq * 8 + 1) * st + nb] = Dn * a0.y;
  out[(bq * 8 + 2) * st + nb] = Dn * a0.z;
  out[(bq * 8 + 3) * st + nb] = Dn * a0.w;
  out[(bq * 8 + 4) * st + nb] = Dn * a1.x;
  out[(bq * 8 + 5) * st + nb] = Dn * a1.y;
  out[(bq * 8 + 6) * st + nb] = Dn * a1.z;
  out[(bq * 8 + 7) * st + nb] = Dn * a1.w;
}

extern "C" void kernel_launch(void* const* d_in, const int* in_sizes, int n_in,
                              void* d_out, int out_size, void* d_ws,
                              size_t ws_size, hipStream_t stream) {
  (void)in_sizes; (void)n_in; (void)out_size; (void)ws_size;
  const float* x = (const float*)d_in[0];
  const float* weight = (const float*)d_in[1];
  const float* att = (const float*)d_in[2];
  const int* node_ids = (const int*)d_in[3];
  float* out = (float*)d_out;

  char* wsb = (char*)d_ws;
  float* es_t = (float*)(wsb);                    // 512KB [m,c,b]
  float* out_e_t = (float*)(wsb + (512 << 10));   // 512KB [m,c,b]
  float* s1_t = (float*)(wsb + (1024 << 10));     // 512KB [n,b]
  int* cntv = (int*)(wsb + (1536 << 10));         // 1MB   [m,n]
  float2* pnb = (float2*)(wsb + (2560 << 10));    // 1MB   [n,b] {mx,invS}
  float* s2 = (float*)(wsb + (3584 << 10));       // 8KB
  float* nrm2 = (float*)(wsb + (3592 << 10));     // 8KB
  float* essum = (float*)(wsb + (3600 << 10));    // 8KB
  float* lossbuf = (float*)(wsb + (3608 << 10));  // 16KB

  k_p1<<<2624, 256, 0, stream>>>(x, weight, att, node_ids, s1_t, es_t, s2,
                                 nrm2, essum, cntv);
  k_p2<<<1536, 256, 0, stream>>>(es_t, nrm2, cntv, s1_t, s2, lossbuf, pnb);
  k_p3<<<2049, 256, 0, stream>>>(x, node_ids, weight, s1_t, s2, pnb, essum,
                                 lossbuf, out_e_t,
                                 out + (size_t)B_SZ * N_NODES * C_DIM);
  k_p4<<<4096, 256, 0, stream>>>(cntv, s1_t, s2, pnb, out_e_t, out);
}